// Round 1
// baseline (1241.357 us; speedup 1.0000x reference)
//
#include <hip/hip_runtime.h>
#include <math.h>

#define T_LEN 4096
#define NBATCH 4
#define DV 512
#define DC 512
#define BT 64
#define SW 576          // stored band width (s - t0 in [0, 576)); decay^512 ~ 1.5e-11 -> negligible truncation
#define NTT 64          // T_LEN / BT
#define EPS_RMS 1.1920929e-07f

__device__ __forceinline__ float wave_sum(float v) {
#pragma unroll
  for (int off = 32; off > 0; off >>= 1) v += __shfl_xor(v, off, 64);
  return v;
}
__device__ __forceinline__ float wave_max(float v) {
#pragma unroll
  for (int off = 32; off > 0; off >>= 1) v = fmaxf(v, __shfl_xor(v, off, 64));
  return v;
}

// ---------------- weight generation: out[i][j] = dot(M1[i,0:128], M2[j,0:128]) ----------------
// which: 0 qw[v][c]=basis.qc  1 kw  2 vw  3 owT[c][v]=oc.basis  4 read logits[v][c]  5 writeT[c][v]
__global__ __launch_bounds__(256) void genw_kernel(
    const float* __restrict__ basis, const float* __restrict__ qc,
    const float* __restrict__ kc, const float* __restrict__ vc,
    const float* __restrict__ oc, const float* __restrict__ rc,
    const float* __restrict__ wc, float* __restrict__ wbuf)
{
  int which = blockIdx.y;
  int idx = blockIdx.x * 256 + threadIdx.x;
  int i = idx >> 9, j = idx & 511;
  const float *M1, *M2;
  switch (which) {
    case 0: M1 = basis; M2 = qc; break;
    case 1: M1 = basis; M2 = kc; break;
    case 2: M1 = basis; M2 = vc; break;
    case 3: M1 = oc;    M2 = basis; break;
    case 4: M1 = basis; M2 = rc; break;
    default: M1 = wc;   M2 = basis; break;
  }
  const float4* r1 = (const float4*)(M1 + (size_t)i * 128);
  const float4* r2 = (const float4*)(M2 + (size_t)j * 128);
  float s = 0.f;
#pragma unroll
  for (int t = 0; t < 32; ++t) {
    float4 a = r1[t], b = r2[t];
    s = fmaf(a.x, b.x, s); s = fmaf(a.y, b.y, s);
    s = fmaf(a.z, b.z, s); s = fmaf(a.w, b.w, s);
  }
  wbuf[(size_t)which * 262144 + idx] = s;
}

// ---------------- in-place column softmax over axis 0 (V) of w[V][C]: one wave per column ----------------
__global__ __launch_bounds__(64) void softmax_col_kernel(float* __restrict__ w)
{
  int c = blockIdx.x;
  int lane = threadIdx.x;
  float v[8];
  float mx = -1e30f;
#pragma unroll
  for (int r = 0; r < 8; ++r) {
    v[r] = w[(size_t)(r * 64 + lane) * DC + c];
    mx = fmaxf(mx, v[r]);
  }
  mx = wave_max(mx);
  float s = 0.f;
#pragma unroll
  for (int r = 0; r < 8; ++r) { v[r] = expf(v[r] - mx); s += v[r]; }
  s = wave_sum(s);
  float inv = 1.f / s;
#pragma unroll
  for (int r = 0; r < 8; ++r) w[(size_t)(r * 64 + lane) * DC + c] = v[r] * inv;
}

// ---------------- per-row rms scale: rs[row] = rsqrt(mean(x^2) + eps); one wave per row ----------------
__global__ __launch_bounds__(256) void rowrms_kernel(const float* __restrict__ x, float* __restrict__ rs)
{
  int row = (blockIdx.x << 2) + (threadIdx.x >> 6);
  int lane = threadIdx.x & 63;
  const float4* p = (const float4*)(x + (size_t)row * DV);
  float4 a = p[lane * 2], b = p[lane * 2 + 1];
  float ss = a.x*a.x + a.y*a.y + a.z*a.z + a.w*a.w
           + b.x*b.x + b.y*b.y + b.z*b.z + b.w*b.w;
  ss = wave_sum(ss);
  if (lane == 0) rs[row] = rsqrtf(ss * (1.f / 512.f) + EPS_RMS);
}

// ---------------- generic 64x64 fp32 GEMM: out = f(alpha*rowscale[m]*(A@B)) (+bias,gelu) (+resid) ----------------
// A row-major [M][lda]; B row-major [K][ldb] (non-transposed). grid = (N/64, M/64).
__global__ __launch_bounds__(256) void gemm64_kernel(
    const float* __restrict__ A, int lda,
    const float* __restrict__ B, int ldb,
    float* __restrict__ out, int ldo,
    const float* __restrict__ resid,
    const float* __restrict__ rowscale,
    const float* __restrict__ bias,
    const float* alpha0, const float* alpha1,
    int K, int do_gelu)
{
  __shared__ float As[32][68];   // As[k][m], pad 4 keeps float4 alignment
  __shared__ float Bs[32][68];   // Bs[k][n]
  int tid = threadIdx.x;
  int m0 = blockIdx.y * 64, n0 = blockIdx.x * 64;
  int tx = tid & 15, ty = tid >> 4;
  float acc[4][4] = {};
  for (int k0 = 0; k0 < K; k0 += 32) {
#pragma unroll
    for (int l = 0; l < 2; ++l) {
      int t = tid + (l << 8);
      int r = t >> 3, c4 = (t & 7) << 2;
      float4 va = *(const float4*)&A[(size_t)(m0 + r) * lda + k0 + c4];
      As[c4 + 0][r] = va.x; As[c4 + 1][r] = va.y;
      As[c4 + 2][r] = va.z; As[c4 + 3][r] = va.w;
      int rb = t >> 4, cb = (t & 15) << 2;
      *(float4*)&Bs[rb][cb] = *(const float4*)&B[(size_t)(k0 + rb) * ldb + n0 + cb];
    }
    __syncthreads();
#pragma unroll
    for (int kk = 0; kk < 32; ++kk) {
      float4 av = *(const float4*)&As[kk][ty << 2];
      float4 bv = *(const float4*)&Bs[kk][tx << 2];
      float a[4] = {av.x, av.y, av.z, av.w};
      float b[4] = {bv.x, bv.y, bv.z, bv.w};
#pragma unroll
      for (int i = 0; i < 4; ++i)
#pragma unroll
        for (int j = 0; j < 4; ++j) acc[i][j] = fmaf(a[i], b[j], acc[i][j]);
    }
    __syncthreads();
  }
  float alpha = 1.f;
  if (alpha0) alpha *= *alpha0;
  if (alpha1) alpha *= *alpha1;
  int mb = m0 + (ty << 2), nb = n0 + (tx << 2);
#pragma unroll
  for (int i = 0; i < 4; ++i) {
    float rsc = alpha * (rowscale ? rowscale[mb + i] : 1.f);
#pragma unroll
    for (int j = 0; j < 4; ++j) {
      float t = acc[i][j] * rsc;
      if (bias) t += bias[nb + j];
      if (do_gelu) t = 0.5f * t * (1.f + erff(t * 0.70710678118654752f));
      size_t o = (size_t)(mb + i) * ldo + nb + j;
      if (resid) t += resid[o];
      out[o] = t;
    }
  }
}

// ---------------- banded scores: sc[tile][i][jb] = (q[t0+i].k[t0+jb]) * decay^(jb-i-1) (0 if jb<=i or s>=T) ----------------
// grid = (SW/64, NTT, NBATCH)
__global__ __launch_bounds__(256) void scoreband_kernel(
    const float* __restrict__ q, const float* __restrict__ k,
    float* __restrict__ sc, const float* decay_logit)
{
  __shared__ float Qs[32][68];
  __shared__ float Ks[32][68];
  int b = blockIdx.z, tt = blockIdx.y, sub = blockIdx.x;
  int t0 = tt * BT;
  int s0 = t0 + sub * 64;
  const float* qb = q + (size_t)b * T_LEN * DC;
  const float* kb = k + (size_t)b * T_LEN * DC;
  int tid = threadIdx.x;
  int tx = tid & 15, ty = tid >> 4;
  float acc[4][4] = {};
  for (int k0 = 0; k0 < DC; k0 += 32) {
#pragma unroll
    for (int l = 0; l < 2; ++l) {
      int t = tid + (l << 8);
      int r = t >> 3, c4 = (t & 7) << 2;
      float4 vq = *(const float4*)&qb[(size_t)(t0 + r) * DC + k0 + c4];
      Qs[c4 + 0][r] = vq.x; Qs[c4 + 1][r] = vq.y;
      Qs[c4 + 2][r] = vq.z; Qs[c4 + 3][r] = vq.w;
      int srow = s0 + r; if (srow > T_LEN - 1) srow = T_LEN - 1;
      float4 vk = *(const float4*)&kb[(size_t)srow * DC + k0 + c4];
      Ks[c4 + 0][r] = vk.x; Ks[c4 + 1][r] = vk.y;
      Ks[c4 + 2][r] = vk.z; Ks[c4 + 3][r] = vk.w;
    }
    __syncthreads();
#pragma unroll
    for (int kk = 0; kk < 32; ++kk) {
      float4 av = *(const float4*)&Qs[kk][ty << 2];
      float4 bv = *(const float4*)&Ks[kk][tx << 2];
      float a[4] = {av.x, av.y, av.z, av.w};
      float b2[4] = {bv.x, bv.y, bv.z, bv.w};
#pragma unroll
      for (int i = 0; i < 4; ++i)
#pragma unroll
        for (int j = 0; j < 4; ++j) acc[i][j] = fmaf(a[i], b2[j], acc[i][j]);
    }
    __syncthreads();
  }
  float dl = *decay_logit;
  float decay = 1.f / (1.f + expf(-dl));
  float l2d = log2f(decay);
  float* scb = sc + ((size_t)(b * NTT + tt)) * BT * SW;
#pragma unroll
  for (int i = 0; i < 4; ++i) {
    int ii = (ty << 2) + i;
#pragma unroll
    for (int j = 0; j < 4; ++j) {
      int jb = sub * 64 + (tx << 2) + j;
      int d = jb - ii;
      int s = t0 + jb;
      float w = (d >= 1 && s < T_LEN) ? exp2f((float)(d - 1) * l2d) : 0.f;
      scb[(size_t)ii * SW + jb] = acc[i][j] * w;
    }
  }
}

// ---------------- retrieved[t0+i][c] = sum_{kk<SW} sc[tile][i][kk] * v[t0+kk][c] ----------------
// grid = (DC/64, NTT, NBATCH)
__global__ __launch_bounds__(256) void retband_kernel(
    const float* __restrict__ sc, const float* __restrict__ v, float* __restrict__ ret)
{
  __shared__ float As[32][68];
  __shared__ float Bs[32][68];
  int b = blockIdx.z, tt = blockIdx.y, nsub = blockIdx.x;
  int t0 = tt * BT, n0 = nsub * 64;
  const float* A = sc + ((size_t)(b * NTT + tt)) * BT * SW;
  const float* vb = v + (size_t)b * T_LEN * DC;
  int tid = threadIdx.x;
  int tx = tid & 15, ty = tid >> 4;
  float acc[4][4] = {};
  for (int k0 = 0; k0 < SW; k0 += 32) {
#pragma unroll
    for (int l = 0; l < 2; ++l) {
      int t = tid + (l << 8);
      int r = t >> 3, c4 = (t & 7) << 2;
      float4 va = *(const float4*)&A[(size_t)r * SW + k0 + c4];
      As[c4 + 0][r] = va.x; As[c4 + 1][r] = va.y;
      As[c4 + 2][r] = va.z; As[c4 + 3][r] = va.w;
      int rb = t >> 4, cb = (t & 15) << 2;
      int srow = t0 + k0 + rb; if (srow > T_LEN - 1) srow = T_LEN - 1;
      *(float4*)&Bs[rb][cb] = *(const float4*)&vb[(size_t)srow * DC + n0 + cb];
    }
    __syncthreads();
#pragma unroll
    for (int kk = 0; kk < 32; ++kk) {
      float4 av = *(const float4*)&As[kk][ty << 2];
      float4 bv = *(const float4*)&Bs[kk][tx << 2];
      float a[4] = {av.x, av.y, av.z, av.w};
      float b2[4] = {bv.x, bv.y, bv.z, bv.w};
#pragma unroll
      for (int i = 0; i < 4; ++i)
#pragma unroll
        for (int j = 0; j < 4; ++j) acc[i][j] = fmaf(a[i], b2[j], acc[i][j]);
    }
    __syncthreads();
  }
  float* rb_ = ret + ((size_t)b * T_LEN + t0) * DC;
#pragma unroll
  for (int i = 0; i < 4; ++i)
#pragma unroll
    for (int j = 0; j < 4; ++j)
      rb_[(size_t)((ty << 2) + i) * DC + n0 + (tx << 2) + j] = acc[i][j];
}

extern "C" void kernel_launch(void* const* d_in, const int* in_sizes, int n_in,
                              void* d_out, int out_size, void* d_ws, size_t ws_size,
                              hipStream_t stream) {
  const float* x       = (const float*)d_in[0];
  const float* basis   = (const float*)d_in[1];
  const float* qc      = (const float*)d_in[2];
  const float* kc      = (const float*)d_in[3];
  const float* vc      = (const float*)d_in[4];
  const float* oc      = (const float*)d_in[5];
  const float* decay_l = (const float*)d_in[6];
  const float* mos     = (const float*)d_in[7];   // mem_out_scale
  const float* rc      = (const float*)d_in[8];
  const float* wc      = (const float*)d_in[9];
  const float* mix     = (const float*)d_in[10];  // [C][C]
  const float* bias    = (const float*)d_in[11];
  const float* oos     = (const float*)d_in[12];  // op_out_scale
  const float* msc     = (const float*)d_in[13];  // mem_scale
  const float* osc     = (const float*)d_in[14];  // op_scale
  float* out = (float*)d_out;

  const size_t WSZ = 512 * 512;            // 262144
  float* ws     = (float*)d_ws;
  float* qw     = ws + 0 * WSZ;            // [V][C]
  float* kw     = ws + 1 * WSZ;
  float* vw     = ws + 2 * WSZ;
  float* owT    = ws + 3 * WSZ;            // [C][V]
  float* readw  = ws + 4 * WSZ;            // [V][C] (softmaxed)
  float* writeT = ws + 5 * WSZ;            // [C][V]
  float* rs     = ws + 6 * WSZ;            // [16384]
  float* qbuf   = rs + 16384;              // [B*T][C]   (later reused as retrieved)
  float* kbuf   = qbuf + (size_t)8388608;  // later reused as tmp
  float* vbuf   = kbuf + (size_t)8388608;  // later reused as vals
  float* sc     = vbuf + (size_t)8388608;  // [B*NTT][64][576]
  const int MROWS = NBATCH * T_LEN;        // 16384

  // 1. weights
  genw_kernel<<<dim3(1024, 6), 256, 0, stream>>>(basis, qc, kc, vc, oc, rc, wc, ws);
  // 2. softmax over V for read_w
  softmax_col_kernel<<<512, 64, 0, stream>>>(readw);
  // 3. rms scales of x
  rowrms_kernel<<<MROWS / 4, 256, 0, stream>>>(x, rs);
  // 4-6. q, k, v projections (rms folded in as row scale)
  gemm64_kernel<<<dim3(8, MROWS / 64), 256, 0, stream>>>(x, DV, qw, DC, qbuf, DC, nullptr, rs, nullptr, nullptr, nullptr, DV, 0);
  gemm64_kernel<<<dim3(8, MROWS / 64), 256, 0, stream>>>(x, DV, kw, DC, kbuf, DC, nullptr, rs, nullptr, nullptr, nullptr, DV, 0);
  gemm64_kernel<<<dim3(8, MROWS / 64), 256, 0, stream>>>(x, DV, vw, DC, vbuf, DC, nullptr, rs, nullptr, nullptr, nullptr, DV, 0);
  // 7. banded decayed scores
  scoreband_kernel<<<dim3(SW / 64, NTT, NBATCH), 256, 0, stream>>>(qbuf, kbuf, sc, decay_l);
  // 8. retrieved = band(scores) @ v  -> reuse qbuf
  retband_kernel<<<dim3(DC / 64, NTT, NBATCH), 256, 0, stream>>>(sc, vbuf, qbuf);
  // 9. x1 = x + mem_scale*mem_out_scale * retrieved @ o_w.T  -> d_out
  gemm64_kernel<<<dim3(8, MROWS / 64), 256, 0, stream>>>(qbuf, DC, owT, DV, out, DV, x, nullptr, nullptr, msc, mos, DC, 0);
  // 10. rms scales of x1
  rowrms_kernel<<<MROWS / 4, 256, 0, stream>>>(out, rs);
  // 11. tmp = rmsnorm(x1) @ read_w -> kbuf
  gemm64_kernel<<<dim3(8, MROWS / 64), 256, 0, stream>>>(out, DV, readw, DC, kbuf, DC, nullptr, rs, nullptr, nullptr, nullptr, DV, 0);
  // 12. vals = gelu(tmp @ channel_mix + bias) -> vbuf
  gemm64_kernel<<<dim3(8, MROWS / 64), 256, 0, stream>>>(kbuf, DC, mix, DC, vbuf, DC, nullptr, nullptr, bias, nullptr, nullptr, DC, 1);
  // 13. out = x1 + op_scale*op_out_scale * vals @ write_w.T (in-place residual)
  gemm64_kernel<<<dim3(8, MROWS / 64), 256, 0, stream>>>(vbuf, DC, writeT, DV, out, DV, out, nullptr, nullptr, osc, oos, DC, 0);
}

// Round 2
// 341.409 us; speedup vs baseline: 3.6360x; 3.6360x over previous
//
#include <hip/hip_runtime.h>
#include <math.h>

typedef __attribute__((ext_vector_type(8))) short bvec8;   // 8 bf16 (4 VGPRs)
typedef __attribute__((ext_vector_type(4))) short bvec4;
typedef __attribute__((ext_vector_type(4))) float fvec4;

#define MROWS 16384
#define TLEN  4096
#define DD    512
#define SWB   640
#define NT128 32
#define EPS_RMS 1.1920929e-07f

#define M_PLAIN 0
#define M_VT    1
#define M_SCORE 2
#define M_RET   3
#define M_F32RES 4
#define M_GELU  5
#define M_F32P  6

__device__ __forceinline__ unsigned short f2bf(float f) {
  unsigned int u = __float_as_uint(f);
  u = (u + 0x7fffu + ((u >> 16) & 1u)) >> 16;   // RNE
  return (unsigned short)u;
}

__device__ __forceinline__ float wred_sum(float v) {
#pragma unroll
  for (int off = 32; off > 0; off >>= 1) v += __shfl_xor(v, off, 64);
  return v;
}
__device__ __forceinline__ float wred_max(float v) {
#pragma unroll
  for (int off = 32; off > 0; off >>= 1) v = fmaxf(v, __shfl_xor(v, off, 64));
  return v;
}

// ---- convert the 7 fp32 param arrays ([512][128]) to bf16 ----
__global__ __launch_bounds__(256) void conv7_kernel(
    const float* __restrict__ basis, const float* __restrict__ qc, const float* __restrict__ kc,
    const float* __restrict__ vc, const float* __restrict__ oc, const float* __restrict__ rc,
    const float* __restrict__ wc,
    unsigned short* __restrict__ basisb, unsigned short* __restrict__ qcb,
    unsigned short* __restrict__ kcb, unsigned short* __restrict__ vcb,
    unsigned short* __restrict__ ocb, unsigned short* __restrict__ rcb,
    unsigned short* __restrict__ wcb)
{
  const float* src; unsigned short* dst;
  switch (blockIdx.y) {
    case 0: src = basis; dst = basisb; break;
    case 1: src = qc; dst = qcb; break;
    case 2: src = kc; dst = kcb; break;
    case 3: src = vc; dst = vcb; break;
    case 4: src = oc; dst = ocb; break;
    case 5: src = rc; dst = rcb; break;
    default: src = wc; dst = wcb; break;
  }
  int idx = blockIdx.x * 256 + threadIdx.x;
  float4 v = ((const float4*)src)[idx];
  union { bvec4 s; unsigned short u[4]; } o;
  o.u[0] = f2bf(v.x); o.u[1] = f2bf(v.y); o.u[2] = f2bf(v.z); o.u[3] = f2bf(v.w);
  ((bvec4*)dst)[idx] = o.s;
}

// ---- xb[m][k] = bf16( x[m][k] * rsqrt(mean(x[m]^2)+eps) ); one wave per row ----
__global__ __launch_bounds__(256) void xbconv_kernel(const float* __restrict__ x,
                                                     unsigned short* __restrict__ xb)
{
  int row = blockIdx.x * 4 + (threadIdx.x >> 6);
  int lane = threadIdx.x & 63;
  const float4* p = (const float4*)(x + (size_t)row * DD);
  float4 a = p[lane * 2], b = p[lane * 2 + 1];
  float ss = a.x*a.x + a.y*a.y + a.z*a.z + a.w*a.w
           + b.x*b.x + b.y*b.y + b.z*b.z + b.w*b.w;
  ss = wred_sum(ss);
  float rs = rsqrtf(ss * (1.f / 512.f) + EPS_RMS);
  union { bvec8 s; unsigned short u[8]; } o;
  o.u[0]=f2bf(a.x*rs); o.u[1]=f2bf(a.y*rs); o.u[2]=f2bf(a.z*rs); o.u[3]=f2bf(a.w*rs);
  o.u[4]=f2bf(b.x*rs); o.u[5]=f2bf(b.y*rs); o.u[6]=f2bf(b.z*rs); o.u[7]=f2bf(b.w*rs);
  *(bvec8*)&xb[(size_t)row * DD + lane * 8] = o.s;
}

// ---- row softmax (512 elems) of fp32 logits -> bf16; one wave per row ----
__global__ __launch_bounds__(256) void softmax_row_kernel(const float* __restrict__ logit,
                                                          unsigned short* __restrict__ outb)
{
  int row = blockIdx.x * 4 + (threadIdx.x >> 6);
  int lane = threadIdx.x & 63;
  const float4* p = (const float4*)(logit + (size_t)row * DD);
  float4 a = p[lane * 2], b = p[lane * 2 + 1];
  float m = fmaxf(fmaxf(fmaxf(a.x, a.y), fmaxf(a.z, a.w)),
                  fmaxf(fmaxf(b.x, b.y), fmaxf(b.z, b.w)));
  m = wred_max(m);
  float e0=expf(a.x-m), e1=expf(a.y-m), e2=expf(a.z-m), e3=expf(a.w-m);
  float e4=expf(b.x-m), e5=expf(b.y-m), e6=expf(b.z-m), e7=expf(b.w-m);
  float s = wred_sum(e0+e1+e2+e3+e4+e5+e6+e7);
  float inv = 1.f / s;
  union { bvec8 sv; unsigned short u[8]; } o;
  o.u[0]=f2bf(e0*inv); o.u[1]=f2bf(e1*inv); o.u[2]=f2bf(e2*inv); o.u[3]=f2bf(e3*inv);
  o.u[4]=f2bf(e4*inv); o.u[5]=f2bf(e5*inv); o.u[6]=f2bf(e6*inv); o.u[7]=f2bf(e7*inv);
  *(bvec8*)&outb[(size_t)row * DD + lane * 8] = o.sv;
}

// ---- mixT[n][k] = bf16(mix[k][n]) ----
__global__ __launch_bounds__(256) void mixT_kernel(const float* __restrict__ mix,
                                                   unsigned short* __restrict__ mt)
{
  int idx = blockIdx.x * 256 + threadIdx.x;
  int n = idx & 511, k = idx >> 9;
  mt[(size_t)n * DD + k] = f2bf(mix[idx]);
}

// ================= MFMA GEMM: C = A[M][K] @ B'[N][K]^T, 128x128 tile, BK=32 =================
// A,B bf16 row-major K-fastest. 256 threads = 4 waves (2x2), each wave 64x64 (4x4 frags).
template<int MODE>
__global__ __launch_bounds__(256) void mfma_gemm(
    const unsigned short* __restrict__ A, int lda,
    const unsigned short* __restrict__ B, int ldb,
    void* outp, int ldo,
    const float* resid,
    const float* __restrict__ bias,
    const float* __restrict__ s0, const float* __restrict__ s1,
    const float* __restrict__ dlog,
    int K)
{
  __shared__ __align__(16) unsigned short As[4096];   // [kg(4)][m(128)][8]
  __shared__ __align__(16) unsigned short Bs[4096];   // [kg(4)][n(128)][8]
  int tid = threadIdx.x;
  int lane = tid & 63, wave = tid >> 6;
  int wm = (wave >> 1) * 64, wn = (wave & 1) * 64;
  int bxx = blockIdx.x, byy = blockIdx.y, bzz = blockIdx.z;

  const unsigned short *Ab, *Bb;
  size_t om, on;
  if constexpr (MODE == M_SCORE) {
    Ab = A + (size_t)(bzz * TLEN + byy * 128) * lda;
    Bb = B + (size_t)(bzz * TLEN + (byy + bxx) * 128) * ldb;
    om = (size_t)(bzz * NT128 + byy) * 128; on = (size_t)bxx * 128;
  } else if constexpr (MODE == M_RET) {
    Ab = A + (size_t)((bzz * NT128 + byy) * 128) * lda;
    Bb = B + (size_t)(bxx * 128) * ldb + (size_t)(bzz * TLEN + byy * 128);
    om = (size_t)(bzz * TLEN + byy * 128); on = (size_t)bxx * 128;
  } else {
    Ab = A + (size_t)(byy * 128) * lda;
    Bb = B + (size_t)(bxx * 128) * ldb;
    om = (size_t)byy * 128; on = (size_t)bxx * 128;
  }

  fvec4 acc[4][4] = {};
  int c0 = tid, c1 = tid + 256;
  int ma0 = c0 & 127, kg0 = c0 >> 7;
  int ma1 = c1 & 127, kg1 = c1 >> 7;

  for (int k0 = 0; k0 < K; k0 += 32) {
    bvec8 ra0 = *(const bvec8*)(Ab + (size_t)ma0 * lda + k0 + kg0 * 8);
    bvec8 ra1 = *(const bvec8*)(Ab + (size_t)ma1 * lda + k0 + kg1 * 8);
    bvec8 rb0 = *(const bvec8*)(Bb + (size_t)ma0 * ldb + k0 + kg0 * 8);
    bvec8 rb1 = *(const bvec8*)(Bb + (size_t)ma1 * ldb + k0 + kg1 * 8);
    __syncthreads();
    *(bvec8*)&As[c0 * 8] = ra0;
    *(bvec8*)&As[c1 * 8] = ra1;
    *(bvec8*)&Bs[c0 * 8] = rb0;
    *(bvec8*)&Bs[c1 * 8] = rb1;
    __syncthreads();
    int kgl = lane >> 4, l15 = lane & 15;
    bvec8 af[4], bfr[4];
#pragma unroll
    for (int i = 0; i < 4; ++i) {
      af[i]  = *(const bvec8*)&As[(size_t)(kgl * 128 + wm + i * 16 + l15) * 8];
      bfr[i] = *(const bvec8*)&Bs[(size_t)(kgl * 128 + wn + i * 16 + l15) * 8];
    }
#pragma unroll
    for (int mi = 0; mi < 4; ++mi)
#pragma unroll
      for (int ni = 0; ni < 4; ++ni)
        acc[mi][ni] = __builtin_amdgcn_mfma_f32_16x16x32_bf16(af[mi], bfr[ni], acc[mi][ni], 0, 0, 0);
  }

  int l15 = lane & 15;
  int lr4 = (lane >> 4) << 2;
  float dlw = 0.f;
  if constexpr (MODE == M_SCORE) {
    float dl = *dlog;
    float dc = 1.f / (1.f + expf(-dl));
    dlw = log2f(dc);
  }
  float alpha = 1.f;
  if constexpr (MODE == M_F32RES) alpha = s0[0] * s1[0];

#pragma unroll
  for (int mi = 0; mi < 4; ++mi) {
#pragma unroll
    for (int ni = 0; ni < 4; ++ni) {
#pragma unroll
      for (int j = 0; j < 4; ++j) {
        int rl = wm + mi * 16 + lr4 + j;   // local row (C/D: row=(lane>>4)*4+j)
        int cl = wn + ni * 16 + l15;       // local col (C/D: col=lane&15)
        float v = acc[mi][ni][j];
        size_t r = om + rl, c = on + cl;
        if constexpr (MODE == M_PLAIN || MODE == M_RET) {
          ((unsigned short*)outp)[r * (size_t)ldo + c] = f2bf(v);
        } else if constexpr (MODE == M_VT) {
          ((unsigned short*)outp)[c * (size_t)ldo + r] = f2bf(v);
        } else if constexpr (MODE == M_SCORE) {
          int d = bxx * 128 + cl - rl;
          int sidx = (byy + bxx) * 128 + cl;
          float w = (d >= 1 && sidx < TLEN) ? exp2f((float)(d - 1) * dlw) : 0.f;
          ((unsigned short*)outp)[r * (size_t)ldo + c] = f2bf(v * w);
        } else if constexpr (MODE == M_F32RES) {
          size_t o = r * (size_t)ldo + c;
          ((float*)outp)[o] = resid[o] + alpha * v;
        } else if constexpr (MODE == M_GELU) {
          float t = v + bias[c];
          float g = 0.5f * t * (1.f + erff(t * 0.70710678118654752f));
          ((unsigned short*)outp)[r * (size_t)ldo + c] = f2bf(g);
        } else { // M_F32P
          ((float*)outp)[r * (size_t)ldo + c] = v;
        }
      }
    }
  }
}

extern "C" void kernel_launch(void* const* d_in, const int* in_sizes, int n_in,
                              void* d_out, int out_size, void* d_ws, size_t ws_size,
                              hipStream_t stream) {
  const float* x       = (const float*)d_in[0];
  const float* basis   = (const float*)d_in[1];
  const float* qc      = (const float*)d_in[2];
  const float* kc      = (const float*)d_in[3];
  const float* vc      = (const float*)d_in[4];
  const float* oc      = (const float*)d_in[5];
  const float* decay_l = (const float*)d_in[6];
  const float* mos     = (const float*)d_in[7];
  const float* rc      = (const float*)d_in[8];
  const float* wc      = (const float*)d_in[9];
  const float* mix     = (const float*)d_in[10];
  const float* bias    = (const float*)d_in[11];
  const float* oos     = (const float*)d_in[12];
  const float* msc     = (const float*)d_in[13];
  const float* osc     = (const float*)d_in[14];
  float* out = (float*)d_out;

  char* w = (char*)d_ws;
  unsigned short* basisb = (unsigned short*)w; w += 65536 * 2;
  unsigned short* qcb    = (unsigned short*)w; w += 65536 * 2;
  unsigned short* kcb    = (unsigned short*)w; w += 65536 * 2;
  unsigned short* vcb    = (unsigned short*)w; w += 65536 * 2;
  unsigned short* ocb    = (unsigned short*)w; w += 65536 * 2;
  unsigned short* rcb    = (unsigned short*)w; w += 65536 * 2;
  unsigned short* wcb    = (unsigned short*)w; w += 65536 * 2;
  unsigned short* qwT = (unsigned short*)w; w += 262144 * 2;  // [c][v]
  unsigned short* kwT = (unsigned short*)w; w += 262144 * 2;  // [c][v]
  unsigned short* vwT = (unsigned short*)w; w += 262144 * 2;  // [c][v]
  unsigned short* owB = (unsigned short*)w; w += 262144 * 2;  // [v][c]
  unsigned short* rdB = (unsigned short*)w; w += 262144 * 2;  // [c][v] softmaxed
  unsigned short* wrB = (unsigned short*)w; w += 262144 * 2;  // [v][c]
  unsigned short* mtB = (unsigned short*)w; w += 262144 * 2;  // [n][k]
  float* readLog = (float*)w; w += 262144 * 4;                // [c][v]
  unsigned short* xb = (unsigned short*)w; w += (size_t)MROWS * DD * 2;
  unsigned short* qb = (unsigned short*)w; w += (size_t)MROWS * DD * 2;
  unsigned short* kb = (unsigned short*)w; w += (size_t)(MROWS + 640) * DD * 2;  // +slack rows
  unsigned short* vT = (unsigned short*)w; w += ((size_t)DD * MROWS + 2048) * 2; // [c][b*T+t] +slack
  unsigned short* sc = (unsigned short*)w; w += (size_t)MROWS * SWB * 2;         // band scores
  unsigned short* ret = (unsigned short*)w; w += (size_t)MROWS * DD * 2;

  // 1. fp32 -> bf16 param conversions
  conv7_kernel<<<dim3(64, 7), 256, 0, stream>>>(basis, qc, kc, vc, oc, rc, wc,
                                                basisb, qcb, kcb, vcb, ocb, rcb, wcb);
  // 2. weight-gen GEMMs (M=N=512, K=128)
  mfma_gemm<M_PLAIN><<<dim3(4, 4), 256, 0, stream>>>(qcb, 128, basisb, 128, qwT, DD, nullptr, nullptr, nullptr, nullptr, nullptr, 128);
  mfma_gemm<M_PLAIN><<<dim3(4, 4), 256, 0, stream>>>(kcb, 128, basisb, 128, kwT, DD, nullptr, nullptr, nullptr, nullptr, nullptr, 128);
  mfma_gemm<M_PLAIN><<<dim3(4, 4), 256, 0, stream>>>(vcb, 128, basisb, 128, vwT, DD, nullptr, nullptr, nullptr, nullptr, nullptr, 128);
  mfma_gemm<M_PLAIN><<<dim3(4, 4), 256, 0, stream>>>(basisb, 128, ocb, 128, owB, DD, nullptr, nullptr, nullptr, nullptr, nullptr, 128);
  mfma_gemm<M_PLAIN><<<dim3(4, 4), 256, 0, stream>>>(basisb, 128, wcb, 128, wrB, DD, nullptr, nullptr, nullptr, nullptr, nullptr, 128);
  mfma_gemm<M_F32P><<<dim3(4, 4), 256, 0, stream>>>(rcb, 128, basisb, 128, readLog, DD, nullptr, nullptr, nullptr, nullptr, nullptr, 128);
  // 3. softmax over v (rows of readLog) -> bf16; mix transpose
  softmax_row_kernel<<<128, 256, 0, stream>>>(readLog, rdB);
  mixT_kernel<<<1024, 256, 0, stream>>>(mix, mtB);
  // 4. xb = bf16(rmsnorm(x))
  xbconv_kernel<<<4096, 256, 0, stream>>>(x, xb);
  // 5. q, k projections; v written transposed
  mfma_gemm<M_PLAIN><<<dim3(4, 128), 256, 0, stream>>>(xb, DD, qwT, DD, qb, DD, nullptr, nullptr, nullptr, nullptr, nullptr, DD);
  mfma_gemm<M_PLAIN><<<dim3(4, 128), 256, 0, stream>>>(xb, DD, kwT, DD, kb, DD, nullptr, nullptr, nullptr, nullptr, nullptr, DD);
  mfma_gemm<M_VT><<<dim3(4, 128), 256, 0, stream>>>(xb, DD, vwT, DD, vT, MROWS, nullptr, nullptr, nullptr, nullptr, nullptr, DD);
  // 6. banded decayed scores (128-row t-tiles, 640-wide band)
  mfma_gemm<M_SCORE><<<dim3(5, NT128, 4), 256, 0, stream>>>(qb, DD, kb, DD, sc, SWB, nullptr, nullptr, nullptr, nullptr, decay_l, DD);
  // 7. retrieved = band(scores) @ v
  mfma_gemm<M_RET><<<dim3(4, NT128, 4), 256, 0, stream>>>(sc, SWB, vT, MROWS, ret, DD, nullptr, nullptr, nullptr, nullptr, nullptr, SWB);
  // 8. x1 = x + mem_scale*mem_out_scale * (retrieved @ o_w.T)
  mfma_gemm<M_F32RES><<<dim3(4, 128), 256, 0, stream>>>(ret, DD, owB, DD, out, DD, x, nullptr, msc, mos, nullptr, DD);
  // 9. xb = bf16(rmsnorm(x1))
  xbconv_kernel<<<4096, 256, 0, stream>>>(out, xb);
  // 10. tmp = xn2 @ read_w
  mfma_gemm<M_PLAIN><<<dim3(4, 128), 256, 0, stream>>>(xb, DD, rdB, DD, qb, DD, nullptr, nullptr, nullptr, nullptr, nullptr, DD);
  // 11. vals = gelu(tmp @ mix + bias)
  mfma_gemm<M_GELU><<<dim3(4, 128), 256, 0, stream>>>(qb, DD, mtB, DD, kb, DD, nullptr, bias, nullptr, nullptr, nullptr, DD);
  // 12. out = x1 + op_scale*op_out_scale * (vals @ write_w.T), in-place residual
  mfma_gemm<M_F32RES><<<dim3(4, 128), 256, 0, stream>>>(kb, DD, wrB, DD, out, DD, out, nullptr, osc, oos, nullptr, DD);
}

// Round 3
// 306.955 us; speedup vs baseline: 4.0441x; 1.1122x over previous
//
#include <hip/hip_runtime.h>
#include <math.h>

typedef __attribute__((ext_vector_type(8))) short bvec8;   // 8 bf16 (4 VGPRs)
typedef __attribute__((ext_vector_type(4))) short bvec4;
typedef __attribute__((ext_vector_type(4))) float fvec4;

#define MROWS 16384
#define TLEN  4096
#define DD    512
#define SWB   640
#define NT128 32
#define EPS_RMS 1.1920929e-07f

#define M_PLAIN  0
#define M_QK     1
#define M_SCORE  2
#define M_RET    3
#define M_F32RES 4
#define M_GELU   5

__device__ __forceinline__ unsigned short f2bf(float f) {
  unsigned int u = __float_as_uint(f);
  u = (u + 0x7fffu + ((u >> 16) & 1u)) >> 16;   // RNE
  return (unsigned short)u;
}

__device__ __forceinline__ float wred_sum(float v) {
#pragma unroll
  for (int off = 32; off > 0; off >>= 1) v += __shfl_xor(v, off, 64);
  return v;
}
__device__ __forceinline__ float wred_max(float v) {
#pragma unroll
  for (int off = 32; off > 0; off >>= 1) v = fmaxf(v, __shfl_xor(v, off, 64));
  return v;
}

// async 16B global->LDS (direct, no VGPR roundtrip)
__device__ __forceinline__ void gload16(const unsigned short* g, unsigned short* l) {
  __builtin_amdgcn_global_load_lds((const __attribute__((address_space(1))) unsigned int*)g,
                                   (__attribute__((address_space(3))) unsigned int*)l,
                                   16, 0, 0);
}

// ---- shared 128x128xK MFMA core; As/Bs layout [kg(4)][row(128)][8] bf16, linear in lane order ----
__device__ __forceinline__ void gemm_core(
    const unsigned short* __restrict__ Ab, int lda,
    const unsigned short* __restrict__ Bb, int ldb,
    unsigned short* As, unsigned short* Bs,
    int K, int tid, int wm, int wn, fvec4 acc[4][4])
{
  int lane = tid & 63, w = tid >> 6;
  int c0 = tid, c1 = tid + 256;
  int r0 = c0 & 127, kg0 = c0 >> 7;
  int r1 = c1 & 127, kg1 = c1 >> 7;
  unsigned short* a0 = As + w * 512;
  unsigned short* a1 = As + 2048 + w * 512;
  unsigned short* b0 = Bs + w * 512;
  unsigned short* b1 = Bs + 2048 + w * 512;
  const unsigned short* Ap0 = Ab + (size_t)r0 * lda + kg0 * 8;
  const unsigned short* Ap1 = Ab + (size_t)r1 * lda + kg1 * 8;
  const unsigned short* Bp0 = Bb + (size_t)r0 * ldb + kg0 * 8;
  const unsigned short* Bp1 = Bb + (size_t)r1 * ldb + kg1 * 8;
  int kgl = lane >> 4, l15 = lane & 15;
  for (int k0 = 0; k0 < K; k0 += 32) {
    __syncthreads();                    // prev tile fully consumed
    gload16(Ap0 + k0, a0);
    gload16(Ap1 + k0, a1);
    gload16(Bp0 + k0, b0);
    gload16(Bp1 + k0, b1);
    asm volatile("s_waitcnt vmcnt(0)" ::: "memory");
    __syncthreads();                    // loads visible to all waves
    bvec8 af[4], bf[4];
#pragma unroll
    for (int i = 0; i < 4; ++i) {
      af[i] = *(const bvec8*)&As[(kgl * 128 + wm + i * 16 + l15) * 8];
      bf[i] = *(const bvec8*)&Bs[(kgl * 128 + wn + i * 16 + l15) * 8];
    }
#pragma unroll
    for (int mi = 0; mi < 4; ++mi)
#pragma unroll
      for (int ni = 0; ni < 4; ++ni)
        acc[mi][ni] = __builtin_amdgcn_mfma_f32_16x16x32_bf16(af[mi], bf[ni], acc[mi][ni], 0, 0, 0);
  }
}

// ---- convert the 7 fp32 param arrays ([512][128]) to bf16 ----
__global__ __launch_bounds__(256) void conv7_kernel(
    const float* __restrict__ basis, const float* __restrict__ qc, const float* __restrict__ kc,
    const float* __restrict__ vc, const float* __restrict__ oc, const float* __restrict__ rc,
    const float* __restrict__ wc,
    unsigned short* __restrict__ basisb, unsigned short* __restrict__ qcb,
    unsigned short* __restrict__ kcb, unsigned short* __restrict__ vcb,
    unsigned short* __restrict__ ocb, unsigned short* __restrict__ rcb,
    unsigned short* __restrict__ wcb)
{
  const float* src; unsigned short* dst;
  switch (blockIdx.y) {
    case 0: src = basis; dst = basisb; break;
    case 1: src = qc; dst = qcb; break;
    case 2: src = kc; dst = kcb; break;
    case 3: src = vc; dst = vcb; break;
    case 4: src = oc; dst = ocb; break;
    case 5: src = rc; dst = rcb; break;
    default: src = wc; dst = wcb; break;
  }
  int idx = blockIdx.x * 256 + threadIdx.x;
  float4 v = ((const float4*)src)[idx];
  union { bvec4 s; unsigned short u[4]; } o;
  o.u[0] = f2bf(v.x); o.u[1] = f2bf(v.y); o.u[2] = f2bf(v.z); o.u[3] = f2bf(v.w);
  ((bvec4*)dst)[idx] = o.s;
}

// ---- fused 6x weight-gen GEMM (512x512, K=128): z selects which ----
__global__ __launch_bounds__(256) void wgen_kernel(
    const unsigned short* __restrict__ basisb, const unsigned short* __restrict__ qcb,
    const unsigned short* __restrict__ kcb, const unsigned short* __restrict__ vcb,
    const unsigned short* __restrict__ ocb, const unsigned short* __restrict__ wcb,
    const unsigned short* __restrict__ rcb,
    unsigned short* __restrict__ qwT, unsigned short* __restrict__ kwT,
    unsigned short* __restrict__ vwT, unsigned short* __restrict__ owB,
    unsigned short* __restrict__ wrB, float* __restrict__ readLog)
{
  __shared__ __align__(16) unsigned short As[4096];
  __shared__ __align__(16) unsigned short Bs[4096];
  int tid = threadIdx.x, lane = tid & 63, wave = tid >> 6;
  int wm = (wave >> 1) * 64, wn = (wave & 1) * 64;
  int z = blockIdx.z;
  const unsigned short *Az, *Bz;
  switch (z) {
    case 0: Az = qcb;    Bz = basisb; break;
    case 1: Az = kcb;    Bz = basisb; break;
    case 2: Az = vcb;    Bz = basisb; break;
    case 3: Az = basisb; Bz = ocb;    break;
    case 4: Az = basisb; Bz = wcb;    break;
    default: Az = rcb;   Bz = basisb; break;
  }
  fvec4 acc[4][4] = {};
  gemm_core(Az + (size_t)blockIdx.y * 128 * 128, 128,
            Bz + (size_t)blockIdx.x * 128 * 128, 128,
            As, Bs, 128, tid, wm, wn, acc);
  int l15 = lane & 15, lr4 = (lane >> 4) << 2;
  int om = blockIdx.y * 128, on = blockIdx.x * 128;
  unsigned short* oz = (z == 0) ? qwT : (z == 1) ? kwT : (z == 2) ? vwT : (z == 3) ? owB : wrB;
#pragma unroll
  for (int mi = 0; mi < 4; ++mi)
#pragma unroll
    for (int ni = 0; ni < 4; ++ni)
#pragma unroll
      for (int j = 0; j < 4; ++j) {
        int r = om + wm + mi * 16 + lr4 + j;
        int c = on + wn + ni * 16 + l15;
        float v = acc[mi][ni][j];
        if (z == 5) readLog[(size_t)r * DD + c] = v;
        else        oz[(size_t)r * DD + c] = f2bf(v);
      }
}

// ---- xb[m][k] = bf16( x[m][k] * rsqrt(mean(x[m]^2)+eps) ); one wave per row ----
__global__ __launch_bounds__(256) void xbconv_kernel(const float* __restrict__ x,
                                                     unsigned short* __restrict__ xb)
{
  int row = blockIdx.x * 4 + (threadIdx.x >> 6);
  int lane = threadIdx.x & 63;
  const float4* p = (const float4*)(x + (size_t)row * DD);
  float4 a = p[lane * 2], b = p[lane * 2 + 1];
  float ss = a.x*a.x + a.y*a.y + a.z*a.z + a.w*a.w
           + b.x*b.x + b.y*b.y + b.z*b.z + b.w*b.w;
  ss = wred_sum(ss);
  float rs = rsqrtf(ss * (1.f / 512.f) + EPS_RMS);
  union { bvec8 s; unsigned short u[8]; } o;
  o.u[0]=f2bf(a.x*rs); o.u[1]=f2bf(a.y*rs); o.u[2]=f2bf(a.z*rs); o.u[3]=f2bf(a.w*rs);
  o.u[4]=f2bf(b.x*rs); o.u[5]=f2bf(b.y*rs); o.u[6]=f2bf(b.z*rs); o.u[7]=f2bf(b.w*rs);
  *(bvec8*)&xb[(size_t)row * DD + lane * 8] = o.s;
}

// ---- row softmax (512 elems) of fp32 logits -> bf16; one wave per row ----
__global__ __launch_bounds__(256) void softmax_row_kernel(const float* __restrict__ logit,
                                                          unsigned short* __restrict__ outb)
{
  int row = blockIdx.x * 4 + (threadIdx.x >> 6);
  int lane = threadIdx.x & 63;
  const float4* p = (const float4*)(logit + (size_t)row * DD);
  float4 a = p[lane * 2], b = p[lane * 2 + 1];
  float m = fmaxf(fmaxf(fmaxf(a.x, a.y), fmaxf(a.z, a.w)),
                  fmaxf(fmaxf(b.x, b.y), fmaxf(b.z, b.w)));
  m = wred_max(m);
  float e0=expf(a.x-m), e1=expf(a.y-m), e2=expf(a.z-m), e3=expf(a.w-m);
  float e4=expf(b.x-m), e5=expf(b.y-m), e6=expf(b.z-m), e7=expf(b.w-m);
  float s = wred_sum(e0+e1+e2+e3+e4+e5+e6+e7);
  float inv = 1.f / s;
  union { bvec8 sv; unsigned short u[8]; } o;
  o.u[0]=f2bf(e0*inv); o.u[1]=f2bf(e1*inv); o.u[2]=f2bf(e2*inv); o.u[3]=f2bf(e3*inv);
  o.u[4]=f2bf(e4*inv); o.u[5]=f2bf(e5*inv); o.u[6]=f2bf(e6*inv); o.u[7]=f2bf(e7*inv);
  *(bvec8*)&outb[(size_t)row * DD + lane * 8] = o.sv;
}

// ---- mixT[n][k] = bf16(mix[k][n]) ----
__global__ __launch_bounds__(256) void mixT_kernel(const float* __restrict__ mix,
                                                   unsigned short* __restrict__ mt)
{
  int idx = blockIdx.x * 256 + threadIdx.x;
  int n = idx & 511, k = idx >> 9;
  mt[(size_t)n * DD + k] = f2bf(mix[idx]);
}

// ================= main MFMA GEMM template =================
template<int MODE>
__global__ __launch_bounds__(256) void mfma_gemm(
    const unsigned short* __restrict__ A, int lda,
    const unsigned short* __restrict__ B, int ldb,
    void* outp, void* out2, int ldo,
    const float* __restrict__ resid,
    const float* __restrict__ bias,
    const float* __restrict__ s0, const float* __restrict__ s1,
    const float* __restrict__ dlog, int K)
{
  __shared__ __align__(16) unsigned short As[4096];
  __shared__ __align__(16) unsigned short Bs[4096];
  int tid = threadIdx.x;
  int lane = tid & 63, wave = tid >> 6;
  int wm = (wave >> 1) * 64, wn = (wave & 1) * 64;
  int bxx = blockIdx.x, byy = blockIdx.y, bzz = blockIdx.z;

  const unsigned short *Ab, *Bb;
  size_t om, on;
  if constexpr (MODE == M_SCORE) {
    Ab = A + (size_t)(bzz * TLEN + byy * 128) * lda;
    Bb = B + (size_t)(bzz * TLEN + (byy + bxx) * 128) * ldb;
    om = (size_t)(bzz * NT128 + byy) * 128; on = (size_t)bxx * 128;
  } else if constexpr (MODE == M_RET) {
    Ab = A + (size_t)((bzz * NT128 + byy) * 128) * lda;
    Bb = B + (size_t)(bxx * 128) * ldb + (size_t)(bzz * TLEN + byy * 128);
    om = (size_t)(bzz * TLEN + byy * 128); on = (size_t)bxx * 128;
  } else {
    Ab = A + (size_t)(byy * 128) * lda;
    Bb = B + (size_t)(bxx * 128) * ldb;
    om = (size_t)byy * 128; on = (size_t)bxx * 128;
  }

  fvec4 acc[4][4] = {};
  gemm_core(Ab, lda, Bb, ldb, As, Bs, K, tid, wm, wn, acc);

  int l15 = lane & 15, lr4 = (lane >> 4) << 2;
  float dlw = 0.f;
  if constexpr (MODE == M_SCORE) {
    float dl = *dlog;
    float dc = 1.f / (1.f + expf(-dl));
    dlw = log2f(dc);
  }
  float alpha = 1.f;
  if constexpr (MODE == M_F32RES) alpha = s0[0] * s1[0];

#pragma unroll
  for (int mi = 0; mi < 4; ++mi) {
#pragma unroll
    for (int ni = 0; ni < 4; ++ni) {
#pragma unroll
      for (int j = 0; j < 4; ++j) {
        int rl = wm + mi * 16 + lr4 + j;
        int cl = wn + ni * 16 + l15;
        float v = acc[mi][ni][j];
        size_t r = om + rl, c = on + cl;
        if constexpr (MODE == M_PLAIN) {
          ((unsigned short*)outp)[r * (size_t)ldo + c] = f2bf(v);
        } else if constexpr (MODE == M_QK) {
          unsigned short* o = (c < 512) ? (unsigned short*)outp : (unsigned short*)out2;
          o[r * 512 + (c & 511)] = f2bf(v);
        } else if constexpr (MODE == M_RET) {
          ((unsigned short*)outp)[r * (size_t)ldo + c] = f2bf(v);
        } else if constexpr (MODE == M_SCORE) {
          int d = bxx * 128 + (int)cl - rl;
          int sidx = (byy + bxx) * 128 + (int)cl;
          float w2 = (d >= 1 && sidx < TLEN) ? exp2f((float)(d - 1) * dlw) : 0.f;
          ((unsigned short*)outp)[r * (size_t)ldo + c] = f2bf(v * w2);
        } else if constexpr (MODE == M_F32RES) {
          size_t o = r * (size_t)ldo + c;
          ((float*)outp)[o] = resid[o] + alpha * v;
        } else { // M_GELU
          float t = v + bias[c];
          float g = 0.5f * t * (1.f + erff(t * 0.70710678118654752f));
          ((unsigned short*)outp)[r * (size_t)ldo + c] = f2bf(g);
        }
      }
    }
  }
}

extern "C" void kernel_launch(void* const* d_in, const int* in_sizes, int n_in,
                              void* d_out, int out_size, void* d_ws, size_t ws_size,
                              hipStream_t stream) {
  const float* x       = (const float*)d_in[0];
  const float* basis   = (const float*)d_in[1];
  const float* qc      = (const float*)d_in[2];
  const float* kc      = (const float*)d_in[3];
  const float* vc      = (const float*)d_in[4];
  const float* oc      = (const float*)d_in[5];
  const float* decay_l = (const float*)d_in[6];
  const float* mos     = (const float*)d_in[7];
  const float* rc      = (const float*)d_in[8];
  const float* wc      = (const float*)d_in[9];
  const float* mix     = (const float*)d_in[10];
  const float* bias    = (const float*)d_in[11];
  const float* oos     = (const float*)d_in[12];
  const float* msc     = (const float*)d_in[13];
  const float* osc     = (const float*)d_in[14];
  float* out = (float*)d_out;

  char* w = (char*)d_ws;
  unsigned short* basisb = (unsigned short*)w; w += 65536 * 2;
  unsigned short* qcb    = (unsigned short*)w; w += 65536 * 2;
  unsigned short* kcb    = (unsigned short*)w; w += 65536 * 2;
  unsigned short* vcb    = (unsigned short*)w; w += 65536 * 2;
  unsigned short* ocb    = (unsigned short*)w; w += 65536 * 2;
  unsigned short* rcb    = (unsigned short*)w; w += 65536 * 2;
  unsigned short* wcb    = (unsigned short*)w; w += 65536 * 2;
  unsigned short* qwT = (unsigned short*)w; w += 262144 * 2;  // [c][v]   (kwT MUST follow)
  unsigned short* kwT = (unsigned short*)w; w += 262144 * 2;  // [c][v]
  unsigned short* vwT = (unsigned short*)w; w += 262144 * 2;  // [c][v]
  unsigned short* owB = (unsigned short*)w; w += 262144 * 2;  // [v][c]
  unsigned short* rdB = (unsigned short*)w; w += 262144 * 2;  // [c][v] softmaxed
  unsigned short* wrB = (unsigned short*)w; w += 262144 * 2;  // [v][c]
  unsigned short* mtB = (unsigned short*)w; w += 262144 * 2;  // [n][k]
  float* readLog = (float*)w; w += 262144 * 4;                // [c][v] fp32
  unsigned short* xb = (unsigned short*)w; w += (size_t)MROWS * DD * 2;
  unsigned short* qb = (unsigned short*)w; w += (size_t)MROWS * DD * 2;
  unsigned short* kb = (unsigned short*)w; w += (size_t)(MROWS + 640) * DD * 2;   // +band slack rows
  unsigned short* vT = (unsigned short*)w; w += ((size_t)DD * MROWS + 2048) * 2;  // [c][b*T+t] +slack
  unsigned short* sc = (unsigned short*)w; w += (size_t)MROWS * SWB * 2;          // band scores
  unsigned short* ret = (unsigned short*)w; w += (size_t)MROWS * DD * 2;

  // 1. fp32 -> bf16 param conversions
  conv7_kernel<<<dim3(64, 7), 256, 0, stream>>>(basis, qc, kc, vc, oc, rc, wc,
                                                basisb, qcb, kcb, vcb, ocb, rcb, wcb);
  // 2. fused weight-gen (6 GEMMs 512x512 K=128)
  wgen_kernel<<<dim3(4, 4, 6), 256, 0, stream>>>(basisb, qcb, kcb, vcb, ocb, wcb, rcb,
                                                 qwT, kwT, vwT, owB, wrB, readLog);
  // 3. softmax over v (rows of readLog) -> bf16; mix transpose
  softmax_row_kernel<<<128, 256, 0, stream>>>(readLog, rdB);
  mixT_kernel<<<1024, 256, 0, stream>>>(mix, mtB);
  // 4. xb = bf16(rmsnorm(x))
  xbconv_kernel<<<4096, 256, 0, stream>>>(x, xb);
  // 5. fused q,k projections (N=1024)
  mfma_gemm<M_QK><<<dim3(8, 128), 256, 0, stream>>>(xb, DD, qwT, DD, qb, kb, DD, nullptr, nullptr, nullptr, nullptr, nullptr, DD);
  // 6. vT[c][t] = (vwT @ xb^T): row-major coalesced output
  mfma_gemm<M_PLAIN><<<dim3(128, 4), 256, 0, stream>>>(vwT, DD, xb, DD, vT, nullptr, MROWS, nullptr, nullptr, nullptr, nullptr, nullptr, DD);
  // 7. banded decayed scores (128-row t-tiles, 640-wide band)
  mfma_gemm<M_SCORE><<<dim3(5, NT128, 4), 256, 0, stream>>>(qb, DD, kb, DD, sc, nullptr, SWB, nullptr, nullptr, nullptr, nullptr, decay_l, DD);
  // 8. retrieved = band(scores) @ v
  mfma_gemm<M_RET><<<dim3(4, NT128, 4), 256, 0, stream>>>(sc, SWB, vT, MROWS, ret, nullptr, DD, nullptr, nullptr, nullptr, nullptr, nullptr, SWB);
  // 9. x1 = x + mem_scale*mem_out_scale * (retrieved @ o_w.T)
  mfma_gemm<M_F32RES><<<dim3(4, 128), 256, 0, stream>>>(ret, DD, owB, DD, out, nullptr, DD, x, nullptr, msc, mos, nullptr, DD);
  // 10. xb = bf16(rmsnorm(x1))
  xbconv_kernel<<<4096, 256, 0, stream>>>(out, xb);
  // 11. tmp = xn2 @ read_w
  mfma_gemm<M_PLAIN><<<dim3(4, 128), 256, 0, stream>>>(xb, DD, rdB, DD, qb, nullptr, DD, nullptr, nullptr, nullptr, nullptr, nullptr, DD);
  // 12. vals = gelu(tmp @ mix + bias)
  mfma_gemm<M_GELU><<<dim3(4, 128), 256, 0, stream>>>(qb, DD, mtB, DD, kb, nullptr, DD, nullptr, bias, nullptr, nullptr, nullptr, DD);
  // 13. out = x1 + op_scale*op_out_scale * (vals @ write_w.T), in-place residual
  mfma_gemm<M_F32RES><<<dim3(4, 128), 256, 0, stream>>>(kb, DD, wrB, DD, out, nullptr, DD, out, nullptr, osc, oos, nullptr, DD);
}

// Round 4
// 279.267 us; speedup vs baseline: 4.4451x; 1.0991x over previous
//
#include <hip/hip_runtime.h>
#include <math.h>

typedef __attribute__((ext_vector_type(8))) short bvec8;   // 8 bf16 (4 VGPRs)
typedef __attribute__((ext_vector_type(4))) short bvec4;
typedef __attribute__((ext_vector_type(4))) float fvec4;

#define MROWS 16384
#define TLEN  4096
#define DD    512
#define SWB   640
#define NT128 32
#define EPS_RMS 1.1920929e-07f

#define M_QKV    0
#define M_SCORE  1
#define M_RET    2
#define M_F32RES 3
#define M_PLAIN  4
#define M_GELU   5

__device__ __forceinline__ unsigned short f2bf(float f) {
  unsigned int u = __float_as_uint(f);
  u = (u + 0x7fffu + ((u >> 16) & 1u)) >> 16;   // RNE
  return (unsigned short)u;
}

__device__ __forceinline__ float wred_sum(float v) {
#pragma unroll
  for (int off = 32; off > 0; off >>= 1) v += __shfl_xor(v, off, 64);
  return v;
}
__device__ __forceinline__ float wred_max(float v) {
#pragma unroll
  for (int off = 32; off > 0; off >>= 1) v = fmaxf(v, __shfl_xor(v, off, 64));
  return v;
}

// bijective XCD-chunk swizzle for 1D grids with n%8==0; chunk = n/8
__device__ __forceinline__ int xcd_swz(int bid, int chunk) {
  return (bid & 7) * chunk + (bid >> 3);
}

// async 16B global->LDS (wave-uniform LDS base + lane*16; global src per-lane)
__device__ __forceinline__ void gload16(const unsigned short* g, unsigned short* l) {
  __builtin_amdgcn_global_load_lds((const __attribute__((address_space(1))) unsigned int*)g,
                                   (__attribute__((address_space(3))) unsigned int*)l,
                                   16, 0, 0);
}

// ---- 128x128xK MFMA core, 3-buffer 2-deep prefetch with counted vmcnt ----
// As/Bs: 3 buffers x 4096 shorts, layout per buffer [kg(4)][row(128)][8]
__device__ __forceinline__ void gemm_core_db(
    const unsigned short* __restrict__ Ab, int lda,
    const unsigned short* __restrict__ Bb, int ldb,
    unsigned short* As, unsigned short* Bs,
    int K, int tid, int wm, int wn, fvec4 acc[4][4])
{
  int lane = tid & 63, w = tid >> 6;
  int r0 = tid & 127;
  int kg0 = tid >> 7;                    // 0 or 1
  const unsigned short* ApA = Ab + (size_t)r0 * lda + kg0 * 8;
  const unsigned short* ApB = ApA + 16;  // kg0+2
  const unsigned short* BpA = Bb + (size_t)r0 * ldb + kg0 * 8;
  const unsigned short* BpB = BpA + 16;
  unsigned short* lA0 = As + w * 512;
  unsigned short* lA1 = As + 2048 + w * 512;
  unsigned short* lB0 = Bs + w * 512;
  unsigned short* lB1 = Bs + 2048 + w * 512;
  int kgl = lane >> 4, l15 = lane & 15;
  int NK = K >> 5;

#define STAGE(kt, buf) do { \
    int _k0 = (kt) << 5; int _o = (buf) * 4096; \
    gload16(ApA + _k0, lA0 + _o); \
    gload16(ApB + _k0, lA1 + _o); \
    gload16(BpA + _k0, lB0 + _o); \
    gload16(BpB + _k0, lB1 + _o); \
  } while (0)

  STAGE(0, 0);
  if (NK > 1) STAGE(1, 1);
  int cur = 0;
  for (int t = 0; t < NK; ++t) {
    if (t + 2 < NK) {
      STAGE(t + 2, cur == 0 ? 2 : cur - 1);          // (cur+2)%3
      asm volatile("s_waitcnt vmcnt(8)" ::: "memory");  // tile t's 4 loads done; 8 stay in flight
    } else if (t + 1 < NK) {
      asm volatile("s_waitcnt vmcnt(4)" ::: "memory");
    } else {
      asm volatile("s_waitcnt vmcnt(0)" ::: "memory");
    }
    __syncthreads();
    const unsigned short* Ac = As + cur * 4096;
    const unsigned short* Bc = Bs + cur * 4096;
    bvec8 af[4], bf[4];
#pragma unroll
    for (int i = 0; i < 4; ++i) {
      af[i] = *(const bvec8*)&Ac[(kgl * 128 + wm + i * 16 + l15) * 8];
      bf[i] = *(const bvec8*)&Bc[(kgl * 128 + wn + i * 16 + l15) * 8];
    }
#pragma unroll
    for (int mi = 0; mi < 4; ++mi)
#pragma unroll
      for (int ni = 0; ni < 4; ++ni)
        acc[mi][ni] = __builtin_amdgcn_mfma_f32_16x16x32_bf16(af[mi], bf[ni], acc[mi][ni], 0, 0, 0);
    __syncthreads();
    cur = (cur == 2) ? 0 : cur + 1;
  }
#undef STAGE
}

// ---- convert the 7 fp32 param arrays ([512][128]) to bf16 ----
__global__ __launch_bounds__(256) void conv7_kernel(
    const float* __restrict__ basis, const float* __restrict__ qc, const float* __restrict__ kc,
    const float* __restrict__ vc, const float* __restrict__ oc, const float* __restrict__ rc,
    const float* __restrict__ wc,
    unsigned short* __restrict__ basisb, unsigned short* __restrict__ qcb,
    unsigned short* __restrict__ kcb, unsigned short* __restrict__ vcb,
    unsigned short* __restrict__ ocb, unsigned short* __restrict__ rcb,
    unsigned short* __restrict__ wcb)
{
  const float* src; unsigned short* dst;
  switch (blockIdx.y) {
    case 0: src = basis; dst = basisb; break;
    case 1: src = qc; dst = qcb; break;
    case 2: src = kc; dst = kcb; break;
    case 3: src = vc; dst = vcb; break;
    case 4: src = oc; dst = ocb; break;
    case 5: src = rc; dst = rcb; break;
    default: src = wc; dst = wcb; break;
  }
  int idx = blockIdx.x * 256 + threadIdx.x;
  float4 v = ((const float4*)src)[idx];
  union { bvec4 s; unsigned short u[4]; } o;
  o.u[0] = f2bf(v.x); o.u[1] = f2bf(v.y); o.u[2] = f2bf(v.z); o.u[3] = f2bf(v.w);
  ((bvec4*)dst)[idx] = o.s;
}

// ---- fused 6x weight-gen GEMM (512x512, K=128): z selects which ----
__global__ __launch_bounds__(256) void wgen_kernel(
    const unsigned short* __restrict__ basisb, const unsigned short* __restrict__ qcb,
    const unsigned short* __restrict__ kcb, const unsigned short* __restrict__ vcb,
    const unsigned short* __restrict__ ocb, const unsigned short* __restrict__ wcb,
    const unsigned short* __restrict__ rcb,
    unsigned short* __restrict__ qwT, unsigned short* __restrict__ kwT,
    unsigned short* __restrict__ vwT, unsigned short* __restrict__ owB,
    unsigned short* __restrict__ wrB, float* __restrict__ readLog)
{
  __shared__ __align__(16) unsigned short As[12288];
  __shared__ __align__(16) unsigned short Bs[12288];
  int tid = threadIdx.x, lane = tid & 63, wave = tid >> 6;
  int wm = (wave >> 1) * 64, wn = (wave & 1) * 64;
  int z = blockIdx.z;
  const unsigned short *Az, *Bz;
  switch (z) {
    case 0: Az = qcb;    Bz = basisb; break;
    case 1: Az = kcb;    Bz = basisb; break;
    case 2: Az = vcb;    Bz = basisb; break;
    case 3: Az = basisb; Bz = ocb;    break;
    case 4: Az = basisb; Bz = wcb;    break;
    default: Az = rcb;   Bz = basisb; break;
  }
  fvec4 acc[4][4] = {};
  gemm_core_db(Az + (size_t)blockIdx.y * 128 * 128, 128,
               Bz + (size_t)blockIdx.x * 128 * 128, 128,
               As, Bs, 128, tid, wm, wn, acc);
  int l15 = lane & 15, lr4 = (lane >> 4) << 2;
  int om = blockIdx.y * 128, on = blockIdx.x * 128;
  unsigned short* oz = (z == 0) ? qwT : (z == 1) ? kwT : (z == 2) ? vwT : (z == 3) ? owB : wrB;
#pragma unroll
  for (int mi = 0; mi < 4; ++mi)
#pragma unroll
    for (int ni = 0; ni < 4; ++ni)
#pragma unroll
      for (int j = 0; j < 4; ++j) {
        int r = om + wm + mi * 16 + lr4 + j;
        int c = on + wn + ni * 16 + l15;
        float v = acc[mi][ni][j];
        if (z == 5) readLog[(size_t)r * DD + c] = v;
        else        oz[(size_t)r * DD + c] = f2bf(v);
      }
}

// ---- xb[m][k] = bf16( x[m][k] * rsqrt(mean(x[m]^2)+eps) ); one wave per row ----
__global__ __launch_bounds__(256) void xbconv_kernel(const float* __restrict__ x,
                                                     unsigned short* __restrict__ xb)
{
  int row = blockIdx.x * 4 + (threadIdx.x >> 6);
  int lane = threadIdx.x & 63;
  const float4* p = (const float4*)(x + (size_t)row * DD);
  float4 a = p[lane * 2], b = p[lane * 2 + 1];
  float ss = a.x*a.x + a.y*a.y + a.z*a.z + a.w*a.w
           + b.x*b.x + b.y*b.y + b.z*b.z + b.w*b.w;
  ss = wred_sum(ss);
  float rs = rsqrtf(ss * (1.f / 512.f) + EPS_RMS);
  union { bvec8 s; unsigned short u[8]; } o;
  o.u[0]=f2bf(a.x*rs); o.u[1]=f2bf(a.y*rs); o.u[2]=f2bf(a.z*rs); o.u[3]=f2bf(a.w*rs);
  o.u[4]=f2bf(b.x*rs); o.u[5]=f2bf(b.y*rs); o.u[6]=f2bf(b.z*rs); o.u[7]=f2bf(b.w*rs);
  *(bvec8*)&xb[(size_t)row * DD + lane * 8] = o.s;
}

// ---- row softmax (512 elems) of fp32 logits -> bf16; one wave per row ----
__global__ __launch_bounds__(256) void softmax_row_kernel(const float* __restrict__ logit,
                                                          unsigned short* __restrict__ outb)
{
  int row = blockIdx.x * 4 + (threadIdx.x >> 6);
  int lane = threadIdx.x & 63;
  const float4* p = (const float4*)(logit + (size_t)row * DD);
  float4 a = p[lane * 2], b = p[lane * 2 + 1];
  float m = fmaxf(fmaxf(fmaxf(a.x, a.y), fmaxf(a.z, a.w)),
                  fmaxf(fmaxf(b.x, b.y), fmaxf(b.z, b.w)));
  m = wred_max(m);
  float e0=expf(a.x-m), e1=expf(a.y-m), e2=expf(a.z-m), e3=expf(a.w-m);
  float e4=expf(b.x-m), e5=expf(b.y-m), e6=expf(b.z-m), e7=expf(b.w-m);
  float s = wred_sum(e0+e1+e2+e3+e4+e5+e6+e7);
  float inv = 1.f / s;
  union { bvec8 sv; unsigned short u[8]; } o;
  o.u[0]=f2bf(e0*inv); o.u[1]=f2bf(e1*inv); o.u[2]=f2bf(e2*inv); o.u[3]=f2bf(e3*inv);
  o.u[4]=f2bf(e4*inv); o.u[5]=f2bf(e5*inv); o.u[6]=f2bf(e6*inv); o.u[7]=f2bf(e7*inv);
  *(bvec8*)&outb[(size_t)row * DD + lane * 8] = o.sv;
}

// ---- mixT[n][k] = bf16(mix[k][n]) ----
__global__ __launch_bounds__(256) void mixT_kernel(const float* __restrict__ mix,
                                                   unsigned short* __restrict__ mt)
{
  int idx = blockIdx.x * 256 + threadIdx.x;
  int n = idx & 511, k = idx >> 9;
  mt[(size_t)n * DD + k] = f2bf(mix[idx]);
}

// ================= main MFMA GEMM, 1D grid + per-mode decode + XCD swizzle =================
template<int MODE>
__global__ __launch_bounds__(256) void mfma1d(
    const unsigned short* __restrict__ A, int lda,
    const unsigned short* __restrict__ B, int ldb,
    const unsigned short* __restrict__ A2,
    void* outp, void* out2, void* out3, int ldo,
    const float* __restrict__ resid, const float* __restrict__ bias,
    const float* __restrict__ s0, const float* __restrict__ s1,
    const float* __restrict__ dlog, int K)
{
  __shared__ __align__(16) unsigned short As[12288];
  __shared__ __align__(16) unsigned short Bs[12288];
  int tid = threadIdx.x, lane = tid & 63, wave = tid >> 6;
  int wm = (wave >> 1) * 64, wn = (wave & 1) * 64;

  const unsigned short *Ab, *Bb;
  size_t om, on;
  int bxx = 0, byy = 0, bzz = 0;
  int vmode = 0;
  int ldoR = ldo;

  if constexpr (MODE == M_QKV) {
    int nb = xcd_swz(blockIdx.x, 192);         // 1536 blocks
    if (nb < 1024) {                           // q|k proj: x-fastest over 8 N-tiles
      Ab = A + (size_t)(nb >> 3) * 128 * 512;
      Bb = B + (size_t)(nb & 7) * 128 * 512;
      om = (size_t)(nb >> 3) * 128; on = (size_t)(nb & 7) * 128;
      ldoR = 512;
    } else {                                   // vT = vwT @ xb^T
      vmode = 1;
      int m = nb - 1024;
      Ab = A2 + (size_t)(m >> 7) * 128 * 512;
      Bb = A + (size_t)(m & 127) * 128 * 512;
      om = (size_t)(m >> 7) * 128; on = (size_t)(m & 127) * 128;
      ldoR = MROWS;
    }
  } else if constexpr (MODE == M_SCORE) {
    int nb = xcd_swz(blockIdx.x, 80);          // 640 blocks
    bxx = nb % 5; int rr = nb / 5; byy = rr & 31; bzz = rr >> 5;
    Ab = A + (size_t)(bzz * TLEN + byy * 128) * lda;
    Bb = B + (size_t)(bzz * TLEN + (byy + bxx) * 128) * ldb;
    om = (size_t)(bzz * NT128 + byy) * 128; on = (size_t)bxx * 128;
  } else if constexpr (MODE == M_RET) {
    int nb = xcd_swz(blockIdx.x, 64);          // 512 blocks
    bxx = nb & 3; int rr = nb >> 2; byy = rr & 31; bzz = rr >> 5;
    Ab = A + (size_t)((bzz * NT128 + byy) * 128) * lda;
    Bb = B + (size_t)(bxx * 128) * ldb + (size_t)(bzz * TLEN + byy * 128);
    om = (size_t)(bzz * TLEN + byy * 128); on = (size_t)bxx * 128;
  } else {
    int nb = xcd_swz(blockIdx.x, 64);          // 512 blocks, x-fastest over 4 N-tiles
    bxx = nb & 3; byy = nb >> 2;
    Ab = A + (size_t)(byy * 128) * lda;
    Bb = B + (size_t)(bxx * 128) * ldb;
    om = (size_t)byy * 128; on = (size_t)bxx * 128;
  }

  fvec4 acc[4][4] = {};
  gemm_core_db(Ab, lda, Bb, ldb, As, Bs, K, tid, wm, wn, acc);

  int l15 = lane & 15, lr4 = (lane >> 4) << 2;
  float dlw = 0.f;
  if constexpr (MODE == M_SCORE) {
    float dl = *dlog;
    float dc = 1.f / (1.f + expf(-dl));
    dlw = log2f(dc);
  }
  float alpha = 1.f;
  if constexpr (MODE == M_F32RES) alpha = s0[0] * s1[0];

#pragma unroll
  for (int mi = 0; mi < 4; ++mi) {
#pragma unroll
    for (int ni = 0; ni < 4; ++ni) {
#pragma unroll
      for (int j = 0; j < 4; ++j) {
        int rl = wm + mi * 16 + lr4 + j;
        int cl = wn + ni * 16 + l15;
        float v = acc[mi][ni][j];
        size_t r = om + rl, c = on + cl;
        if constexpr (MODE == M_QKV) {
          if (vmode == 0) {
            unsigned short* o = (c < 512) ? (unsigned short*)outp : (unsigned short*)out2;
            o[r * 512 + (c & 511)] = f2bf(v);
          } else {
            ((unsigned short*)out3)[r * (size_t)MROWS + c] = f2bf(v);
          }
        } else if constexpr (MODE == M_SCORE) {
          int d = bxx * 128 + (int)cl - rl;
          int sidx = (byy + bxx) * 128 + (int)cl;
          float w2 = (d >= 1 && sidx < TLEN) ? exp2f((float)(d - 1) * dlw) : 0.f;
          ((unsigned short*)outp)[r * (size_t)ldoR + c] = f2bf(v * w2);
        } else if constexpr (MODE == M_F32RES) {
          size_t o = r * (size_t)ldoR + c;
          ((float*)outp)[o] = resid[o] + alpha * v;
        } else if constexpr (MODE == M_GELU) {
          float t = v + bias[c];
          float g = 0.5f * t * (1.f + erff(t * 0.70710678118654752f));
          ((unsigned short*)outp)[r * (size_t)ldoR + c] = f2bf(g);
        } else { // M_RET / M_PLAIN
          ((unsigned short*)outp)[r * (size_t)ldoR + c] = f2bf(v);
        }
      }
    }
  }
}

extern "C" void kernel_launch(void* const* d_in, const int* in_sizes, int n_in,
                              void* d_out, int out_size, void* d_ws, size_t ws_size,
                              hipStream_t stream) {
  const float* x       = (const float*)d_in[0];
  const float* basis   = (const float*)d_in[1];
  const float* qc      = (const float*)d_in[2];
  const float* kc      = (const float*)d_in[3];
  const float* vc      = (const float*)d_in[4];
  const float* oc      = (const float*)d_in[5];
  const float* decay_l = (const float*)d_in[6];
  const float* mos     = (const float*)d_in[7];
  const float* rc      = (const float*)d_in[8];
  const float* wc      = (const float*)d_in[9];
  const float* mix     = (const float*)d_in[10];
  const float* bias    = (const float*)d_in[11];
  const float* oos     = (const float*)d_in[12];
  const float* msc     = (const float*)d_in[13];
  const float* osc     = (const float*)d_in[14];
  float* out = (float*)d_out;

  char* w = (char*)d_ws;
  unsigned short* basisb = (unsigned short*)w; w += 65536 * 2;
  unsigned short* qcb    = (unsigned short*)w; w += 65536 * 2;
  unsigned short* kcb    = (unsigned short*)w; w += 65536 * 2;
  unsigned short* vcb    = (unsigned short*)w; w += 65536 * 2;
  unsigned short* ocb    = (unsigned short*)w; w += 65536 * 2;
  unsigned short* rcb    = (unsigned short*)w; w += 65536 * 2;
  unsigned short* wcb    = (unsigned short*)w; w += 65536 * 2;
  unsigned short* qwT = (unsigned short*)w; w += 262144 * 2;  // [c][v]   (kwT MUST follow)
  unsigned short* kwT = (unsigned short*)w; w += 262144 * 2;  // [c][v]
  unsigned short* vwT = (unsigned short*)w; w += 262144 * 2;  // [c][v]
  unsigned short* owB = (unsigned short*)w; w += 262144 * 2;  // [v][c]
  unsigned short* rdB = (unsigned short*)w; w += 262144 * 2;  // [c][v] softmaxed
  unsigned short* wrB = (unsigned short*)w; w += 262144 * 2;  // [v][c]
  unsigned short* mtB = (unsigned short*)w; w += 262144 * 2;  // [n][k]
  float* readLog = (float*)w; w += 262144 * 4;                // [c][v] fp32
  unsigned short* xb = (unsigned short*)w; w += (size_t)MROWS * DD * 2;
  unsigned short* qb = (unsigned short*)w; w += (size_t)MROWS * DD * 2;
  unsigned short* kb = (unsigned short*)w; w += (size_t)(MROWS + 640) * DD * 2;   // +band slack rows
  unsigned short* vT = (unsigned short*)w; w += ((size_t)DD * MROWS + 2048) * 2;  // [c][b*T+t] +slack
  unsigned short* sc = (unsigned short*)w; w += (size_t)MROWS * SWB * 2;          // band scores
  unsigned short* ret = (unsigned short*)w; w += (size_t)MROWS * DD * 2;

  // 1. fp32 -> bf16 param conversions
  conv7_kernel<<<dim3(64, 7), 256, 0, stream>>>(basis, qc, kc, vc, oc, rc, wc,
                                                basisb, qcb, kcb, vcb, ocb, rcb, wcb);
  // 2. fused weight-gen (6 GEMMs 512x512 K=128)
  wgen_kernel<<<dim3(4, 4, 6), 256, 0, stream>>>(basisb, qcb, kcb, vcb, ocb, wcb, rcb,
                                                 qwT, kwT, vwT, owB, wrB, readLog);
  // 3. softmax over v (rows of readLog) -> bf16; mix transpose
  softmax_row_kernel<<<128, 256, 0, stream>>>(readLog, rdB);
  mixT_kernel<<<1024, 256, 0, stream>>>(mix, mtB);
  // 4. xb = bf16(rmsnorm(x))
  xbconv_kernel<<<4096, 256, 0, stream>>>(x, xb);
  // 5. fused q,k,vT projections (one 1536-block launch)
  mfma1d<M_QKV><<<1536, 256, 0, stream>>>(xb, DD, qwT, DD, vwT, qb, kb, vT, DD,
                                          nullptr, nullptr, nullptr, nullptr, nullptr, DD);
  // 6. banded decayed scores (128-row t-tiles, 640-wide band)
  mfma1d<M_SCORE><<<640, 256, 0, stream>>>(qb, DD, kb, DD, nullptr, sc, nullptr, nullptr, SWB,
                                           nullptr, nullptr, nullptr, nullptr, decay_l, DD);
  // 7. retrieved = band(scores) @ v
  mfma1d<M_RET><<<512, 256, 0, stream>>>(sc, SWB, vT, MROWS, nullptr, ret, nullptr, nullptr, DD,
                                         nullptr, nullptr, nullptr, nullptr, nullptr, SWB);
  // 8. x1 = x + mem_scale*mem_out_scale * (retrieved @ o_w.T)
  mfma1d<M_F32RES><<<512, 256, 0, stream>>>(ret, DD, owB, DD, nullptr, out, nullptr, nullptr, DD,
                                            x, nullptr, msc, mos, nullptr, DD);
  // 9. xb = bf16(rmsnorm(x1))
  xbconv_kernel<<<4096, 256, 0, stream>>>(out, xb);
  // 10. tmp = xn2 @ read_w
  mfma1d<M_PLAIN><<<512, 256, 0, stream>>>(xb, DD, rdB, DD, nullptr, qb, nullptr, nullptr, DD,
                                           nullptr, nullptr, nullptr, nullptr, nullptr, DD);
  // 11. vals = gelu(tmp @ mix + bias)
  mfma1d<M_GELU><<<512, 256, 0, stream>>>(qb, DD, mtB, DD, nullptr, kb, nullptr, nullptr, DD,
                                          nullptr, bias, nullptr, nullptr, nullptr, DD);
  // 12. out = x1 + op_scale*op_out_scale * (vals @ write_w.T), in-place residual
  mfma1d<M_F32RES><<<512, 256, 0, stream>>>(kb, DD, wrB, DD, nullptr, out, nullptr, nullptr, DD,
                                            out, nullptr, osc, oos, nullptr, DD);
}